// Round 7
// baseline (445.831 us; speedup 1.0000x reference)
//
#include <hip/hip_runtime.h>
#include <hip/hip_bf16.h>
#include <hip/hip_fp16.h>

// ---------------------------------------------------------------------------
// Abbe lithography forward — single fused persistent kernel.
// Math: doses factor out (I(d)=d^2 I(1)); all shift phases cancel in |AA|^2;
// weight cancels against norm_I; +/- source pairs give identical |AA|^2
// (W Hermitian about window center + odd-symmetric f32 FM grid) -> merged.
// Phases (device-scope grid barrier between):
//   A : block 0: weights+pair-merge+compaction+scale      -> ws header
//   B1: row FFT of mask, keep 241 window cols             -> R1t[beta][y]
//   B2: col FFT, keep 241 window rows                     -> W[alpha][beta]
//   C1: per source row IDFT of (W.*P)*sqrt(w)/512         -> T2[s][x][a] fp16
//   C2: per source col IDFT, acc[wv][x][y] = sum |AA'|^2  (single pass)
//   D : scale (x512^2 refold), 3 doses, resist sigmoid
// FFT-512: radix-8, 3 stages, one wave per FFT, wave-level sync only;
// LDS exchange: writes 2-way (free), reads contiguous ds_read_b128.
// Output reg u of lane L holds X[(L>>3) + 8*(L&7) + 64*u].
// Co-residency: grid=512, __launch_bounds__(256,2) -> 2 blocks/CU capacity;
// grid barrier: monotonic counter, 1 atomicAdd/block, threadfence both sides.
// ---------------------------------------------------------------------------

#define NBLK 512
#define SPLIT 4

static const size_t O_BAR  = 2048;                       // barrier counter
static const size_t O_ACC  = 8192;                       // SPLIT*512*512*f32
static const size_t ACC_BYTES = (size_t)SPLIT * 512 * 512 * 4;
static const size_t O_WIN  = O_ACC + ACC_BYTES;          // 4202496
static const size_t O_R1   = O_WIN + 464896;             // 4667392
static const size_t O_T2   = O_R1 + 987136;              // 5654528
static const size_t SLOT_BYTES = (size_t)512 * 244 * 4;  // half2 slots

__device__ inline float2 cadd(float2 a, float2 b){ return make_float2(a.x+b.x, a.y+b.y); }
__device__ inline float2 csub(float2 a, float2 b){ return make_float2(a.x-b.x, a.y-b.y); }
__device__ inline float2 cmul(float2 a, float2 b){
  return make_float2(fmaf(a.x, b.x, -(a.y*b.y)), fmaf(a.x, b.y, a.y*b.x));
}
__device__ inline float2 twsgn(float2 t, int S) {
  return make_float2(t.x, (S > 0) ? t.y : -t.y);
}

__device__ inline void gridbar(int* cnt, int gen) {
  __syncthreads();
  if (threadIdx.x == 0) {
    __threadfence();                              // release (invalidates L1 too)
    atomicAdd(cnt, 1);                            // device-scope on CDNA
    int target = (gen + 1) * NBLK;
    while (__hip_atomic_load(cnt, __ATOMIC_ACQUIRE, __HIP_MEMORY_SCOPE_AGENT) < target)
      __builtin_amdgcn_s_sleep(2);
    __threadfence();                              // acquire
  }
  __syncthreads();
}

// Radix-8 butterfly. If ZTOP, v[4..7] are known zero (skips first add level).
template<int S, bool ZTOP>
__device__ inline void dft8(float2 v[8]) {
  const float sg = (float)S;
  const float C7 = 0.7071067811865476f;
  float2 t0, t1, t2, t3, t4, t5, t6, t7;
  if (ZTOP) {
    t0 = v[0]; t4 = v[0];
    t1 = v[1]; t5 = v[1];
    t2 = v[2]; t6 = v[2];
    t3 = v[3]; t7 = v[3];
  } else {
    t0=cadd(v[0],v[4]); t4=csub(v[0],v[4]);
    t1=cadd(v[1],v[5]); t5=csub(v[1],v[5]);
    t2=cadd(v[2],v[6]); t6=csub(v[2],v[6]);
    t3=cadd(v[3],v[7]); t7=csub(v[3],v[7]);
  }
  t5 = make_float2(C7*(t5.x - sg*t5.y), C7*(t5.y + sg*t5.x));
  t6 = make_float2(-sg*t6.y, sg*t6.x);
  t7 = make_float2(C7*(-t7.x - sg*t7.y), C7*(sg*t7.x - t7.y));
  float2 u0=cadd(t0,t2), u2=csub(t0,t2);
  float2 u1=cadd(t1,t3), u3=csub(t1,t3);
  u3 = make_float2(-sg*u3.y, sg*u3.x);
  float2 u4=cadd(t4,t6), u6=csub(t4,t6);
  float2 u5=cadd(t5,t7), u7=csub(t5,t7);
  u7 = make_float2(-sg*u7.y, sg*u7.x);
  v[0]=cadd(u0,u1); v[4]=csub(u0,u1);
  v[2]=cadd(u2,u3); v[6]=csub(u2,u3);
  v[1]=cadd(u4,u5); v[5]=csub(u4,u5);
  v[3]=cadd(u6,u7); v[7]=csub(u6,u7);
}

// One-wave FFT-512; xch = per-wave float2[544] (16B aligned). Wave-sync only.
template<int S, bool ZTOP>
__device__ inline void wfft512(float2 v[8], int lane, float2* xch,
                               const float2* twt) {
  const int p2 = lane & 7, u0 = lane >> 3;
  dft8<S, ZTOP>(v);
  { float2 t1 = twsgn(twt[lane], S), acc = t1;
    v[1] = cmul(v[1], acc);
    #pragma unroll
    for (int u = 2; u < 8; u++) { acc = cmul(acc, t1); v[u] = cmul(v[u], acc); } }
  __builtin_amdgcn_wave_barrier();
  #pragma unroll
  for (int u = 0; u < 8; u++) xch[u*68 + p2*8 + u0] = v[u];
  __builtin_amdgcn_wave_barrier();
  { const float4* rp = (const float4*)(xch + u0*68 + p2*8);
    #pragma unroll
    for (int q = 0; q < 4; q++) {
      float4 t = rp[q];
      v[2*q]   = make_float2(t.x, t.y);
      v[2*q+1] = make_float2(t.z, t.w);
    } }
  dft8<S, false>(v);
  { float2 t1 = twsgn(twt[p2 << 3], S), acc = t1;
    v[1] = cmul(v[1], acc);
    #pragma unroll
    for (int u = 2; u < 8; u++) { acc = cmul(acc, t1); v[u] = cmul(v[u], acc); } }
  __builtin_amdgcn_wave_barrier();
  #pragma unroll
  for (int u = 0; u < 8; u++) xch[u*68 + lane] = v[u];
  __builtin_amdgcn_wave_barrier();
  { const float4* rp = (const float4*)(xch + p2*68 + u0*8);
    #pragma unroll
    for (int q = 0; q < 4; q++) {
      float4 t = rp[q];
      v[2*q]   = make_float2(t.x, t.y);
      v[2*q+1] = make_float2(t.z, t.w);
    } }
  dft8<S, false>(v);
}

// LDS arena: twt[512] f2 @0 (4096B) | xch 4x544 f2 @4096 (17408B) |
// FM[241] f @21504 (1024B pad). Phase-A scratch + phase-D tile overlay xch.
#define ARENA_BYTES (4096 + 17408 + 1024)

__global__ void __launch_bounds__(256, 2)
k_fused(const float* __restrict__ mask, const float* __restrict__ prm,
        const float* __restrict__ sfx, const float* __restrict__ sfy,
        char* __restrict__ ws, float* __restrict__ out) {
  __shared__ __align__(16) char arena[ARENA_BYTES];
  float2* twt = (float2*)arena;
  float2* lds = (float2*)(arena + 4096);
  float*  FMt = (float*)(arena + 4096 + 17408);
  int*    bar = (int*)(ws + O_BAR);
  float*  wsf = (float*)ws;
  int t = threadIdx.x, lane = t & 63, wv = t >> 6, b = blockIdx.x;

  float*   acc = (float*)(ws + O_ACC);
  float2*  Wg  = (float2*)(ws + O_WIN);
  float2*  R1t = (float2*)(ws + O_R1);
  __half2* T2  = (__half2*)(ws + O_T2);

  // per-block tables (persist all phases)
  for (int k = t; k < 512; k += 256) {
    double a = 6.283185307179586476925286766559 * (double)k / 512.0;
    twt[k] = make_float2((float)cos(a), (float)sin(a));
  }
  if (t < 241) FMt[t] = (float)(((double)(t - 120)) / 100.0);

  // --- phase A: block 0 computes weights/pairs/scale into ws header --------
  if (b == 0) {
    float*  sw   = (float*)(arena + 4096);          // 169 f
    float*  sx_  = sw + 192;
    float*  sy_  = sx_ + 192;
    float*  scw  = sy_ + 192;
    double* so   = (double*)(arena + 4096 + 3072);  // 8-aligned
    int*    skp  = (int*)(arena + 4096 + 3072 + 1408);
    if (t < 169) {
      float p = prm[t];
      float val = 1.f / (1.f + __expf(-8.f * p));
      float w = (val >= 0.001f) ? val : 0.f;
      double o = 0.0; float fx = 0.f, fy = 0.f;
      if (w > 0.f) {
        fx = sfx[t]; fy = sfy[t];
        double f2 = (double)fx*(double)fx + (double)fy*(double)fy;
        o = (double)w * sqrt((1.0 - 0.11390625 * f2) / (1.0 - 0.87890625 * f2));
      }
      sw[t] = w; so[t] = o; sx_[t] = fx; sy_[t] = fy;
    }
    __syncthreads();
    if (t < 169) {                      // merge s with s'=(-fx,-fy): exact
      float w = sw[t];
      int keep = 0; float cw = w;
      if (w > 0.f) {
        float fx = sx_[t], fy = sy_[t];
        int pr = -1;
        for (int s2 = 0; s2 < 169; s2++) {
          if (sw[s2] > 0.f && fabsf(sx_[s2] + fx) < 1e-5f
                           && fabsf(sy_[s2] + fy) < 1e-5f) { pr = s2; break; }
        }
        if (pr < 0 || pr == t) keep = 1;
        else if (pr > t) { keep = 1; cw = w + sw[pr]; }
      }
      skp[t] = keep; scw[t] = cw;
    }
    __syncthreads();
    if (t == 0) {
      double Sden = 0.0; int c = 0;
      for (int s = 0; s < 169; s++) {
        Sden += so[s];                               // norm over ALL valid
        if (skp[s]) { wsf[64+c] = scw[s]; wsf[320+c] = sx_[s]; wsf[576+c] = sy_[s]; c++; }
      }
      ((int*)ws)[0] = c;
      wsf[1] = (float)(1.0 / (262144.0 * 1.44 * Sden));  // 512^2 refold
    }
  }
  gridbar(bar, 0);

  // --- phase B1: row FFT of mask (blocks 0..127, y = b*4+wv) ---------------
  if (b < 128) {
    int y = b * 4 + wv;
    float2 v[8];
    #pragma unroll
    for (int q = 0; q < 8; q++) v[q] = make_float2(mask[y*512 + 64*q + lane], 0.f);
    wfft512<-1, false>(v, lane, lds + wv*544, twt);
    #pragma unroll
    for (int u = 0; u < 8; u++) {
      int k = (lane>>3) + 8*(lane&7) + 64*u;
      int beta = (k >= 392) ? (k - 392) : ((k <= 120) ? (k + 120) : -1);
      if (beta >= 0) R1t[beta*512 + y] = v[u];
    }
  }
  gridbar(bar, 1);

  // --- phase B2: col FFT -> W[alpha][beta] (blocks 0..60) ------------------
  if (b < 61) {
    int j = b * 4 + wv;                      // 0..243
    float2 v[8];
    #pragma unroll
    for (int q = 0; q < 8; q++)
      v[q] = (j < 241) ? R1t[j*512 + 64*q + lane] : make_float2(0.f, 0.f);
    wfft512<-1, false>(v, lane, lds + wv*544, twt);
    if (j < 241) {
      #pragma unroll
      for (int u = 0; u < 8; u++) {
        int k = (lane>>3) + 8*(lane&7) + 64*u;
        int alpha = (k >= 392) ? (k - 392) : ((k <= 120) ? (k + 120) : -1);
        if (alpha >= 0) Wg[alpha*241 + j] = v[u];
      }
    }
  }
  gridbar(bar, 2);

  int count = *(volatile int*)ws;            // fresh after fenced barrier

  // --- phase C1: per source row IDFT -> T2 (fp16), task=(sic,tile) ---------
  for (int task = b; task < count * 31; task += NBLK) {
    int sic  = task / 31;
    int tile = task % 31;
    float fx = wsf[320 + sic], fy = wsf[576 + sic];
    float sqw = __fsqrt_rn(wsf[64 + sic]) * 0.001953125f;  // sqrt(w)/512
    float2* xch = lds + wv*544;
    #pragma unroll
    for (int ph = 0; ph < 2; ph++) {
      int alpha = tile*8 + ph*4 + wv;
      bool arow = (alpha < 241);
      float Gf = __fadd_rn(arow ? FMt[alpha] : 0.f, fy);
      float g2 = __fmul_rn(Gf, Gf);
      bool active = arow && (g2 <= 1.0f);    // fl(G^2)>1 -> row all-zero
      float2 v[8];
      #pragma unroll
      for (int q = 0; q < 8; q++) v[q] = make_float2(0.f, 0.f);
      if (active) {
        #pragma unroll
        for (int q = 0; q < 4; q++) {        // n<241 -> q<4 only
          int n = 64*q + lane;
          if (n < 241) {
            float Ff = __fadd_rn(FMt[n], fx);
            float r2 = __fadd_rn(__fmul_rn(Ff, Ff), g2);  // np f32 semantics
            if (r2 <= 1.0f) {
              float num = fmaf(-0.11390625f, r2, 1.0f);
              float den = fmaf(-0.87890625f, r2, 1.0f);
              float P = __fsqrt_rn(__fsqrt_rn(__fdividef(num, den))) * sqw;
              float2 Wv = Wg[alpha*241 + n];
              v[q] = make_float2(P * Wv.x, P * Wv.y);
            }
          }
        }
        wfft512<1, true>(v, lane, xch, twt);
      }
      #pragma unroll
      for (int u = 0; u < 8; u++) {
        int xx = (lane>>3) + 8*(lane&7) + 64*u;
        xch[xx] = v[u];                      // zeros when inactive
      }
      __syncthreads();
      int colb = tile*8 + ph*4;
      if (colb < 244) {                      // tile30/ph1 would spill: skip
        #pragma unroll
        for (int r = 0; r < 2; r++) {
          int x = t + 256*r;
          union { __half2 h[4]; float4 f; } u;
          #pragma unroll
          for (int wvi = 0; wvi < 4; wvi++) {
            float2 a = lds[wvi*544 + x];
            u.h[wvi] = __floats2half2_rn(a.x, a.y);
          }
          *(float4*)(T2 + ((size_t)sic*512 + x)*244 + colb) = u.f;
        }
      }
      __syncthreads();
    }
  }
  gridbar(bar, 3);

  // --- phase C2: col IDFT, acc[wv][x][y] = sum |AA'|^2 (x = b) -------------
  {
    int x = b;
    float2* xch = lds + wv*544;
    float av[8] = {0.f,0.f,0.f,0.f,0.f,0.f,0.f,0.f};
    int sic = wv;
    bool act = (sic < count);
    __half2 pv[4] = {{0.f,0.f},{0.f,0.f},{0.f,0.f},{0.f,0.f}};
    if (act) {
      const __half2* row = T2 + ((size_t)sic*512 + x)*244;
      #pragma unroll
      for (int q = 0; q < 4; q++) {
        int n = 64*q + lane;
        pv[q] = (n < 241) ? row[n] : __half2{0.f, 0.f};
      }
    }
    while (act) {
      float2 v[8];
      #pragma unroll
      for (int q = 0; q < 4; q++) { float2 f = __half22float2(pv[q]); v[q] = f; }
      #pragma unroll
      for (int q = 4; q < 8; q++) v[q] = make_float2(0.f, 0.f);
      int nsic = sic + SPLIT;
      act = (nsic < count);
      if (act) {                             // prefetch across the FFT
        const __half2* row = T2 + ((size_t)nsic*512 + x)*244;
        #pragma unroll
        for (int q = 0; q < 4; q++) {
          int n = 64*q + lane;
          pv[q] = (n < 241) ? row[n] : __half2{0.f, 0.f};
        }
      }
      wfft512<1, true>(v, lane, xch, twt);
      #pragma unroll
      for (int u = 0; u < 8; u++)
        av[u] += fmaf(v[u].x, v[u].x, v[u].y*v[u].y);
      sic = nsic;
    }
    float* a = acc + ((size_t)wv << 18) + (size_t)x * 512;
    int y0 = (lane>>3) + 8*(lane&7);
    #pragma unroll
    for (int u = 0; u < 8; u++) a[y0 + 64*u] = av[u];   // single pass: store
  }
  gridbar(bar, 4);

  // --- phase D: transpose-tile, scale, doses, resist (blocks 0..63) --------
  if (b < 64) {
    float (*tile)[65] = (float (*)[65])lds;  // 64x65 f overlay on xch
    float scale = wsf[1];
    int x0 = (b & 7) * 64, y0 = (b >> 3) * 64;
    int j = lane, i0 = wv;
    #pragma unroll
    for (int k = 0; k < 16; k++) {
      int i = i0 + 4*k;
      const float* ap = acc + (size_t)(x0 + i)*512 + y0 + j;
      float s = 0.f;
      #pragma unroll
      for (int p = 0; p < SPLIT; p++) s += ap[(size_t)p << 18];
      tile[i][j] = s;
    }
    __syncthreads();
    const float dd[3] = {0.9604f, 1.0f, 1.0404f};
    #pragma unroll
    for (int k = 0; k < 16; k++) {
      int yy = i0 + 4*k;
      float I = scale * tile[j][yy];
      int o = (y0 + yy)*512 + x0 + j;
      #pragma unroll
      for (int d = 0; d < 3; d++) {
        float Ik = dd[d] * I;
        out[(size_t)d*262144 + o] = Ik;
        out[(size_t)(3+d)*262144 + o] = 1.f / (1.f + __expf(-30.f*(Ik - 0.225f)));
      }
    }
  }
}

extern "C" void kernel_launch(void* const* d_in, const int* in_sizes, int n_in,
                              void* d_out, int out_size, void* d_ws, size_t ws_size,
                              hipStream_t stream) {
  (void)in_sizes; (void)n_in; (void)out_size; (void)ws_size;
  const float* mask = (const float*)d_in[0];
  const float* prm  = (const float*)d_in[1];
  const float* sfx  = (const float*)d_in[2];
  const float* sfy  = (const float*)d_in[3];
  char* ws = (char*)d_ws;
  hipMemsetAsync(ws + O_BAR, 0, 64, stream);           // barrier counter = 0
  k_fused<<<dim3(NBLK), dim3(256), 0, stream>>>(mask, prm, sfx, sfy, ws,
                                                (float*)d_out);
}

// Round 8
// 158.920 us; speedup vs baseline: 2.8054x; 2.8054x over previous
//
#include <hip/hip_runtime.h>
#include <hip/hip_bf16.h>
#include <hip/hip_fp16.h>

// ---------------------------------------------------------------------------
// Abbe lithography forward — single fused persistent kernel, v2.
// Math: doses factor out (I(d)=d^2 I(1)); shift phases cancel in |AA|^2;
// weight cancels against norm_I; +/- source pairs merged (exact, Hermitian W
// + odd-symmetric f32 FM grid).
// XCD-coherence strategy (v1 post-mortem: __threadfence/acquire = per-block
// L2 wb/inv storm = 76us/barrier): ALL cross-block data uses RELAXED
// AGENT-scope atomic loads/stores (bypass non-coherent L2, coherent at LLC);
// barriers are fence-free: __syncthreads' compiler-emitted vmcnt(0) drain
// guarantees sc1 stores are at LLC before the arrival add.
// Barrier: 64 spread arrival counters (128B apart) <- 1 relaxed add/block;
// block0/wave0 polls counters (1 lane each, __all), publishes relaxed flag.
// Phases: A(per-block setup, LDS-local) ; B1 row FFT -> R1t ; bar ;
//         B2 col FFT -> W ; bar ; C1 row IDFT -> T2 fp16 ; bar ;
//         C2 col IDFT acc=sum|AA|^2 ; bar ; D scale+doses+resist.
// FFT-512: radix-8, 3 stages, one wave per FFT, wave-level sync only.
// Output reg u of lane L holds X[(L>>3) + 8*(L&7) + 64*u].
// Co-residency: grid=512, __launch_bounds__(256,2) (verified: v1 completed).
// ---------------------------------------------------------------------------

#define NBLK 512
#define SPLIT 4

static const size_t O_FLG  = 2048;
static const size_t O_CTR  = 4096;                       // 64 ints, 128B apart
static const size_t O_ACC  = 16384;                      // SPLIT*512*512*f32
static const size_t ACC_BYTES = (size_t)SPLIT * 512 * 512 * 4;
static const size_t O_WIN  = O_ACC + ACC_BYTES;
static const size_t O_R1   = O_WIN + 464896;
static const size_t O_T2   = O_R1 + 987136;

// --- relaxed agent-scope accessors (LLC-coherent, no cache maintenance) ----
__device__ inline void ag_store_u64(void* p, unsigned long long v) {
  __hip_atomic_store((unsigned long long*)p, v, __ATOMIC_RELAXED,
                     __HIP_MEMORY_SCOPE_AGENT);
}
__device__ inline unsigned long long ag_load_u64(const void* p) {
  return __hip_atomic_load((unsigned long long*)p, __ATOMIC_RELAXED,
                           __HIP_MEMORY_SCOPE_AGENT);
}
__device__ inline void ag_store_f2(void* p, float2 v) {
  union { float2 f; unsigned long long u; } c; c.f = v;
  ag_store_u64(p, c.u);
}
__device__ inline float2 ag_load_f2(const void* p) {
  union { unsigned long long u; float2 f; } c; c.u = ag_load_u64(p);
  return c.f;
}
__device__ inline void ag_store_u32(void* p, unsigned v) {
  __hip_atomic_store((unsigned*)p, v, __ATOMIC_RELAXED, __HIP_MEMORY_SCOPE_AGENT);
}
__device__ inline unsigned ag_load_u32(const void* p) {
  return __hip_atomic_load((unsigned*)p, __ATOMIC_RELAXED, __HIP_MEMORY_SCOPE_AGENT);
}

// Fence-free grid barrier (see header). gen = 0,1,2,...
__device__ inline void gridbar(char* ws, int b, int t, int lane, int wv, int gen) {
  __syncthreads();               // compiler drains vmcnt(0): stores are at LLC
  int* ctr = (int*)(ws + O_CTR);
  int* flg = (int*)(ws + O_FLG);
  if (t == 0)
    __hip_atomic_fetch_add(&ctr[(b & 63) * 32], 1, __ATOMIC_RELAXED,
                           __HIP_MEMORY_SCOPE_AGENT);
  if (b == 0 && wv == 0) {
    int target = (NBLK / 64) * (gen + 1);
    for (;;) {
      int v = __hip_atomic_load(&ctr[lane * 32], __ATOMIC_RELAXED,
                                __HIP_MEMORY_SCOPE_AGENT);
      if (__all(v >= target)) break;
      __builtin_amdgcn_s_sleep(1);
    }
    if (lane == 0)
      __hip_atomic_store(flg, gen + 1, __ATOMIC_RELAXED, __HIP_MEMORY_SCOPE_AGENT);
  }
  if (t == 0) {
    while (__hip_atomic_load(flg, __ATOMIC_RELAXED, __HIP_MEMORY_SCOPE_AGENT)
           < gen + 1)
      __builtin_amdgcn_s_sleep(1);
  }
  __syncthreads();
}

__device__ inline float2 cadd(float2 a, float2 b){ return make_float2(a.x+b.x, a.y+b.y); }
__device__ inline float2 csub(float2 a, float2 b){ return make_float2(a.x-b.x, a.y-b.y); }
__device__ inline float2 cmul(float2 a, float2 b){
  return make_float2(fmaf(a.x, b.x, -(a.y*b.y)), fmaf(a.x, b.y, a.y*b.x));
}
__device__ inline float2 twsgn(float2 t, int S) {
  return make_float2(t.x, (S > 0) ? t.y : -t.y);
}

template<int S, bool ZTOP>
__device__ inline void dft8(float2 v[8]) {
  const float sg = (float)S;
  const float C7 = 0.7071067811865476f;
  float2 t0, t1, t2, t3, t4, t5, t6, t7;
  if (ZTOP) {
    t0 = v[0]; t4 = v[0];
    t1 = v[1]; t5 = v[1];
    t2 = v[2]; t6 = v[2];
    t3 = v[3]; t7 = v[3];
  } else {
    t0=cadd(v[0],v[4]); t4=csub(v[0],v[4]);
    t1=cadd(v[1],v[5]); t5=csub(v[1],v[5]);
    t2=cadd(v[2],v[6]); t6=csub(v[2],v[6]);
    t3=cadd(v[3],v[7]); t7=csub(v[3],v[7]);
  }
  t5 = make_float2(C7*(t5.x - sg*t5.y), C7*(t5.y + sg*t5.x));
  t6 = make_float2(-sg*t6.y, sg*t6.x);
  t7 = make_float2(C7*(-t7.x - sg*t7.y), C7*(sg*t7.x - t7.y));
  float2 u0=cadd(t0,t2), u2=csub(t0,t2);
  float2 u1=cadd(t1,t3), u3=csub(t1,t3);
  u3 = make_float2(-sg*u3.y, sg*u3.x);
  float2 u4=cadd(t4,t6), u6=csub(t4,t6);
  float2 u5=cadd(t5,t7), u7=csub(t5,t7);
  u7 = make_float2(-sg*u7.y, sg*u7.x);
  v[0]=cadd(u0,u1); v[4]=csub(u0,u1);
  v[2]=cadd(u2,u3); v[6]=csub(u2,u3);
  v[1]=cadd(u4,u5); v[5]=csub(u4,u5);
  v[3]=cadd(u6,u7); v[7]=csub(u6,u7);
}

// One-wave FFT-512; xch = per-wave float2[544] (16B aligned). Wave-sync only.
template<int S, bool ZTOP>
__device__ inline void wfft512(float2 v[8], int lane, float2* xch,
                               const float2* twt) {
  const int p2 = lane & 7, u0 = lane >> 3;
  dft8<S, ZTOP>(v);
  { float2 t1 = twsgn(twt[lane], S), acc = t1;
    v[1] = cmul(v[1], acc);
    #pragma unroll
    for (int u = 2; u < 8; u++) { acc = cmul(acc, t1); v[u] = cmul(v[u], acc); } }
  __builtin_amdgcn_wave_barrier();
  #pragma unroll
  for (int u = 0; u < 8; u++) xch[u*68 + p2*8 + u0] = v[u];
  __builtin_amdgcn_wave_barrier();
  { const float4* rp = (const float4*)(xch + u0*68 + p2*8);
    #pragma unroll
    for (int q = 0; q < 4; q++) {
      float4 t = rp[q];
      v[2*q]   = make_float2(t.x, t.y);
      v[2*q+1] = make_float2(t.z, t.w);
    } }
  dft8<S, false>(v);
  { float2 t1 = twsgn(twt[p2 << 3], S), acc = t1;
    v[1] = cmul(v[1], acc);
    #pragma unroll
    for (int u = 2; u < 8; u++) { acc = cmul(acc, t1); v[u] = cmul(v[u], acc); } }
  __builtin_amdgcn_wave_barrier();
  #pragma unroll
  for (int u = 0; u < 8; u++) xch[u*68 + lane] = v[u];
  __builtin_amdgcn_wave_barrier();
  { const float4* rp = (const float4*)(xch + p2*68 + u0*8);
    #pragma unroll
    for (int q = 0; q < 4; q++) {
      float4 t = rp[q];
      v[2*q]   = make_float2(t.x, t.y);
      v[2*q+1] = make_float2(t.z, t.w);
    } }
  dft8<S, false>(v);
}

// LDS arena layout
#define A_TWT 0                         // 512 float2      (4096 B)
#define A_XCH 4096                      // 4x544 float2    (17408 B)
#define A_FMT 21504                     // 241 float + pad (1024 B)
#define A_SRC 22528                     // cw/cfx/cfy[176] (2112 B)
#define A_MET 24640                     // int count; float scale
#define ARENA_BYTES 24704

__global__ void __launch_bounds__(256, 2)
k_fused(const float* __restrict__ mask, const float* __restrict__ prm,
        const float* __restrict__ sfx, const float* __restrict__ sfy,
        char* __restrict__ ws, float* __restrict__ out) {
  __shared__ __align__(16) char arena[ARENA_BYTES];
  float2* twt = (float2*)(arena + A_TWT);
  float2* lds = (float2*)(arena + A_XCH);
  float*  FMt = (float*)(arena + A_FMT);
  int t = threadIdx.x, lane = t & 63, wv = t >> 6, b = blockIdx.x;

  float*   acc = (float*)(ws + O_ACC);
  float2*  Wg  = (float2*)(ws + O_WIN);
  float2*  R1t = (float2*)(ws + O_R1);
  __half2* T2  = (__half2*)(ws + O_T2);

  // tables (persist all phases)
  for (int k = t; k < 512; k += 256) {
    double a = 6.283185307179586476925286766559 * (double)k / 512.0;
    twt[k] = make_float2((float)cos(a), (float)sin(a));
  }
  if (t < 241) FMt[t] = (float)(((double)(t - 120)) / 100.0);

  // --- phase A: per-block setup (LDS-local, replicated; deterministic) -----
  {
    float*  sw  = (float*)(arena + A_XCH);
    float*  sxx = (float*)(arena + A_XCH + 768);
    float*  syy = (float*)(arena + A_XCH + 1536);
    double* so  = (double*)(arena + A_XCH + 2304);
    int*    skp = (int*)(arena + A_XCH + 3712);
    float*  scw = (float*)(arena + A_XCH + 4416);
    if (t < 169) {
      float p = prm[t];
      float val = 1.f / (1.f + __expf(-8.f * p));
      float w = (val >= 0.001f) ? val : 0.f;
      double o = 0.0; float fx = 0.f, fy = 0.f;
      if (w > 0.f) {
        fx = sfx[t]; fy = sfy[t];
        double f2 = (double)fx*(double)fx + (double)fy*(double)fy;
        o = (double)w * sqrt((1.0 - 0.11390625 * f2) / (1.0 - 0.87890625 * f2));
      }
      sw[t] = w; so[t] = o; sxx[t] = fx; syy[t] = fy;
    }
    __syncthreads();
    if (t < 169) {                      // merge s with s'=(-fx,-fy): exact
      float w = sw[t];
      int keep = 0; float cw = w;
      if (w > 0.f) {
        float fx = sxx[t], fy = syy[t];
        int pr = -1;
        for (int s2 = 0; s2 < 169; s2++) {
          if (sw[s2] > 0.f && fabsf(sxx[s2] + fx) < 1e-5f
                           && fabsf(syy[s2] + fy) < 1e-5f) { pr = s2; break; }
        }
        if (pr < 0 || pr == t) keep = 1;
        else if (pr > t) { keep = 1; cw = w + sw[pr]; }
      }
      skp[t] = keep; scw[t] = cw;
    }
    __syncthreads();
    if (t == 0) {
      float* cw  = (float*)(arena + A_SRC);
      float* cfx = cw + 176; float* cfy = cw + 352;
      double Sden = 0.0; int c = 0;
      for (int s = 0; s < 169; s++) {
        Sden += so[s];                               // norm over ALL valid
        if (skp[s]) { cw[c] = scw[s]; cfx[c] = sxx[s]; cfy[c] = syy[s]; c++; }
      }
      *(int*)(arena + A_MET) = c;
      *(float*)(arena + A_MET + 4) =
          (float)(1.0 / (262144.0 * 1.44 * Sden));   // 512^2 refold
    }
    __syncthreads();                   // A scratch dead; tables ready
  }
  const float* cw  = (const float*)(arena + A_SRC);
  const float* cfx = cw + 176;
  const float* cfy = cw + 352;
  int count = *(const int*)(arena + A_MET);
  float scale = *(const float*)(arena + A_MET + 4);

  // --- phase B1: row FFT of mask (blocks 0..127, y = b*4+wv) ---------------
  if (b < 128) {
    int y = b * 4 + wv;
    float2 v[8];
    #pragma unroll
    for (int q = 0; q < 8; q++) v[q] = make_float2(mask[y*512 + 64*q + lane], 0.f);
    wfft512<-1, false>(v, lane, lds + wv*544, twt);
    #pragma unroll
    for (int u = 0; u < 8; u++) {
      int k = (lane>>3) + 8*(lane&7) + 64*u;
      int beta = (k >= 392) ? (k - 392) : ((k <= 120) ? (k + 120) : -1);
      if (beta >= 0) ag_store_f2(&R1t[beta*512 + y], v[u]);
    }
  }
  gridbar(ws, b, t, lane, wv, 0);

  // --- phase B2: col FFT -> W[alpha][beta] (blocks 0..60) ------------------
  if (b < 61) {
    int j = b * 4 + wv;                      // 0..243
    float2 v[8];
    #pragma unroll
    for (int q = 0; q < 8; q++)
      v[q] = (j < 241) ? ag_load_f2(&R1t[j*512 + 64*q + lane])
                       : make_float2(0.f, 0.f);
    wfft512<-1, false>(v, lane, lds + wv*544, twt);
    if (j < 241) {
      #pragma unroll
      for (int u = 0; u < 8; u++) {
        int k = (lane>>3) + 8*(lane&7) + 64*u;
        int alpha = (k >= 392) ? (k - 392) : ((k <= 120) ? (k + 120) : -1);
        if (alpha >= 0) ag_store_f2(&Wg[alpha*241 + j], v[u]);
      }
    }
  }
  gridbar(ws, b, t, lane, wv, 1);

  // --- phase C1: per source row IDFT -> T2 (fp16), task=(sic,tile) ---------
  for (int task = b; task < count * 31; task += NBLK) {
    int sic  = task / 31;
    int tile = task % 31;
    float fx = cfx[sic], fy = cfy[sic];
    float sqw = __fsqrt_rn(cw[sic]) * 0.001953125f;  // sqrt(w)/512
    float2* xch = lds + wv*544;
    #pragma unroll
    for (int ph = 0; ph < 2; ph++) {
      int alpha = tile*8 + ph*4 + wv;
      bool arow = (alpha < 241);
      float Gf = __fadd_rn(arow ? FMt[alpha] : 0.f, fy);
      float g2 = __fmul_rn(Gf, Gf);
      bool active = arow && (g2 <= 1.0f);    // fl(G^2)>1 -> row all-zero
      float2 v[8];
      #pragma unroll
      for (int q = 0; q < 8; q++) v[q] = make_float2(0.f, 0.f);
      if (active) {
        #pragma unroll
        for (int q = 0; q < 4; q++) {        // n<241 -> q<4 only
          int n = 64*q + lane;
          if (n < 241) {
            float Ff = __fadd_rn(FMt[n], fx);
            float r2 = __fadd_rn(__fmul_rn(Ff, Ff), g2);  // np f32 semantics
            if (r2 <= 1.0f) {
              float num = fmaf(-0.11390625f, r2, 1.0f);
              float den = fmaf(-0.87890625f, r2, 1.0f);
              float P = __fsqrt_rn(__fsqrt_rn(__fdividef(num, den))) * sqw;
              float2 Wv = ag_load_f2(&Wg[alpha*241 + n]);
              v[q] = make_float2(P * Wv.x, P * Wv.y);
            }
          }
        }
        wfft512<1, true>(v, lane, xch, twt);
      }
      #pragma unroll
      for (int u = 0; u < 8; u++) {
        int xx = (lane>>3) + 8*(lane&7) + 64*u;
        xch[xx] = v[u];                      // zeros when inactive
      }
      __syncthreads();
      int colb = tile*8 + ph*4;
      if (colb < 244) {                      // tile30/ph1 would spill: skip
        #pragma unroll
        for (int r = 0; r < 2; r++) {
          int x = t + 256*r;
          union { __half2 h[4]; unsigned long long u64[2]; } uu;
          #pragma unroll
          for (int wvi = 0; wvi < 4; wvi++) {
            float2 a = lds[wvi*544 + x];
            uu.h[wvi] = __floats2half2_rn(a.x, a.y);
          }
          char* dst = (char*)(T2 + ((size_t)sic*512 + x)*244 + colb);
          ag_store_u64(dst,     uu.u64[0]);
          ag_store_u64(dst + 8, uu.u64[1]);
        }
      }
      __syncthreads();
    }
  }
  gridbar(ws, b, t, lane, wv, 2);

  // --- phase C2: col IDFT, acc[wv][x][y] = sum |AA'|^2 (x = b) -------------
  {
    int x = b;
    float2* xch = lds + wv*544;
    float av[8] = {0.f,0.f,0.f,0.f,0.f,0.f,0.f,0.f};
    int sic = wv;
    bool act = (sic < count);
    union { unsigned u; __half2 h; } pv[4];
    #pragma unroll
    for (int q = 0; q < 4; q++) pv[q].u = 0;
    if (act) {
      const __half2* row = T2 + ((size_t)sic*512 + x)*244;
      #pragma unroll
      for (int q = 0; q < 4; q++) {
        int n = 64*q + lane;
        if (n < 241) pv[q].u = ag_load_u32(row + n);
      }
    }
    while (act) {
      float2 v[8];
      #pragma unroll
      for (int q = 0; q < 4; q++) { float2 f = __half22float2(pv[q].h); v[q] = f; }
      #pragma unroll
      for (int q = 4; q < 8; q++) v[q] = make_float2(0.f, 0.f);
      int nsic = sic + SPLIT;
      act = (nsic < count);
      #pragma unroll
      for (int q = 0; q < 4; q++) pv[q].u = 0;
      if (act) {                             // prefetch across the FFT
        const __half2* row = T2 + ((size_t)nsic*512 + x)*244;
        #pragma unroll
        for (int q = 0; q < 4; q++) {
          int n = 64*q + lane;
          if (n < 241) pv[q].u = ag_load_u32(row + n);
        }
      }
      wfft512<1, true>(v, lane, xch, twt);
      #pragma unroll
      for (int u = 0; u < 8; u++)
        av[u] += fmaf(v[u].x, v[u].x, v[u].y*v[u].y);
      sic = nsic;
    }
    float* a = acc + ((size_t)wv << 18) + (size_t)x * 512;
    int y0 = (lane>>3) + 8*(lane&7);
    #pragma unroll
    for (int u = 0; u < 8; u++)
      ag_store_u32(a + y0 + 64*u, __float_as_uint(av[u]));
  }
  gridbar(ws, b, t, lane, wv, 3);

  // --- phase D: transpose-tile, scale, doses, resist (blocks 0..63) --------
  if (b < 64) {
    float (*tile)[65] = (float (*)[65])(arena + A_XCH);  // 64x65 f overlay
    int x0 = (b & 7) * 64, y0 = (b >> 3) * 64;
    int j = lane, i0 = wv;
    #pragma unroll
    for (int k = 0; k < 16; k++) {
      int i = i0 + 4*k;
      const float* ap = acc + (size_t)(x0 + i)*512 + y0 + j;
      float s = 0.f;
      #pragma unroll
      for (int p = 0; p < SPLIT; p++)
        s += __uint_as_float(ag_load_u32(ap + ((size_t)p << 18)));
      tile[i][j] = s;
    }
    __syncthreads();
    const float dd[3] = {0.9604f, 1.0f, 1.0404f};
    #pragma unroll
    for (int k = 0; k < 16; k++) {
      int yy = i0 + 4*k;
      float I = scale * tile[j][yy];
      int o = (y0 + yy)*512 + x0 + j;
      #pragma unroll
      for (int d = 0; d < 3; d++) {
        float Ik = dd[d] * I;
        out[(size_t)d*262144 + o] = Ik;
        out[(size_t)(3+d)*262144 + o] = 1.f / (1.f + __expf(-30.f*(Ik - 0.225f)));
      }
    }
  }
}

extern "C" void kernel_launch(void* const* d_in, const int* in_sizes, int n_in,
                              void* d_out, int out_size, void* d_ws, size_t ws_size,
                              hipStream_t stream) {
  (void)in_sizes; (void)n_in; (void)out_size; (void)ws_size;
  const float* mask = (const float*)d_in[0];
  const float* prm  = (const float*)d_in[1];
  const float* sfx  = (const float*)d_in[2];
  const float* sfy  = (const float*)d_in[3];
  char* ws = (char*)d_ws;
  hipMemsetAsync(ws + O_FLG, 0, O_ACC - O_FLG, stream); // flag + counters = 0
  k_fused<<<dim3(NBLK), dim3(256), 0, stream>>>(mask, prm, sfx, sfy, ws,
                                                (float*)d_out);
}

// Round 9
// 138.243 us; speedup vs baseline: 3.2250x; 1.1496x over previous
//
#include <hip/hip_runtime.h>
#include <hip/hip_bf16.h>
#include <hip/hip_fp16.h>

// ---------------------------------------------------------------------------
// Abbe lithography forward — multi-kernel (R6 structure, storm-fixed).
// Math: doses factor out (I(d)=d^2 I(1)); shift phases cancel in |AA|^2;
// weight cancels against norm_I; +/- source pairs merged (exact: Hermitian W
// about window center + odd-symmetric f32 FM grid).
//   B1: block0 does setup (weights+pair-merge+scale -> ws hdr); all blocks
//       row FFT of mask, keep 241 window cols        -> R1t[beta][y]
//   B2: col FFT, keep 241 window rows                -> W[alpha][beta]
//   C1: task-loop grid (no empty-dispatch storm): per source row IDFT of
//       (W.*P)*sqrt(w)/512                           -> T2[s][x][alpha] fp16
//       rows with fl(G^2)>1 provably all-zero -> skip FFT, store zeros.
//   C2: per source col IDFT, acc[part][x][y] = sum |AA'|^2
//   D : scale (x512^2 refold), 3 doses, resist sigmoid (LDS transpose)
// FFT-512: radix-8, 3 stages, one wave per FFT, wave-level sync only;
// LDS exchange: writes 2-way (free), reads contiguous ds_read_b128.
// Output reg u of lane L holds X[(L>>3) + 8*(L&7) + 64*u].
// Twiddle (f64-built) + FM tables are built per block in LDS (~0.4us).
// ---------------------------------------------------------------------------

#define SPLIT 8

static const size_t O_ACC  = 8192;                       // SPLIT*512*512*f32
static const size_t ACC_BYTES = (size_t)SPLIT * 512 * 512 * 4;
static const size_t O_WIN  = O_ACC + ACC_BYTES;
static const size_t O_R1   = O_WIN + 464896;
static const size_t O_T2   = O_R1 + 987136;
static const size_t SLOT_BYTES = (size_t)512 * 244 * 4;  // half2 slots

__device__ inline float2 cadd(float2 a, float2 b){ return make_float2(a.x+b.x, a.y+b.y); }
__device__ inline float2 csub(float2 a, float2 b){ return make_float2(a.x-b.x, a.y-b.y); }
__device__ inline float2 cmul(float2 a, float2 b){
  return make_float2(fmaf(a.x, b.x, -(a.y*b.y)), fmaf(a.x, b.y, a.y*b.x));
}
__device__ inline float2 twsgn(float2 t, int S) {
  return make_float2(t.x, (S > 0) ? t.y : -t.y);
}

// Per-block twiddle table exp(+2*pi*i*k/512), f64-built (256-thread blocks).
__device__ inline void build_twt(float2* twt) {
  for (int k = (int)threadIdx.x; k < 512; k += 256) {
    double a = 6.283185307179586476925286766559 * (double)k / 512.0;
    twt[k] = make_float2((float)cos(a), (float)sin(a));
  }
}

// Radix-8 butterfly. If ZTOP, v[4..7] are known zero (skips first add level).
template<int S, bool ZTOP>
__device__ inline void dft8(float2 v[8]) {
  const float sg = (float)S;
  const float C7 = 0.7071067811865476f;
  float2 t0, t1, t2, t3, t4, t5, t6, t7;
  if (ZTOP) {
    t0 = v[0]; t4 = v[0];
    t1 = v[1]; t5 = v[1];
    t2 = v[2]; t6 = v[2];
    t3 = v[3]; t7 = v[3];
  } else {
    t0=cadd(v[0],v[4]); t4=csub(v[0],v[4]);
    t1=cadd(v[1],v[5]); t5=csub(v[1],v[5]);
    t2=cadd(v[2],v[6]); t6=csub(v[2],v[6]);
    t3=cadd(v[3],v[7]); t7=csub(v[3],v[7]);
  }
  t5 = make_float2(C7*(t5.x - sg*t5.y), C7*(t5.y + sg*t5.x));
  t6 = make_float2(-sg*t6.y, sg*t6.x);
  t7 = make_float2(C7*(-t7.x - sg*t7.y), C7*(sg*t7.x - t7.y));
  float2 u0=cadd(t0,t2), u2=csub(t0,t2);
  float2 u1=cadd(t1,t3), u3=csub(t1,t3);
  u3 = make_float2(-sg*u3.y, sg*u3.x);
  float2 u4=cadd(t4,t6), u6=csub(t4,t6);
  float2 u5=cadd(t5,t7), u7=csub(t5,t7);
  u7 = make_float2(-sg*u7.y, sg*u7.x);
  v[0]=cadd(u0,u1); v[4]=csub(u0,u1);
  v[2]=cadd(u2,u3); v[6]=csub(u2,u3);
  v[1]=cadd(u4,u5); v[5]=csub(u4,u5);
  v[3]=cadd(u6,u7); v[7]=csub(u6,u7);
}

// One-wave FFT-512; xch = per-wave float2[544] (16B aligned). Wave-sync only.
template<int S, bool ZTOP>
__device__ inline void wfft512(float2 v[8], int lane, float2* xch,
                               const float2* twt) {
  const int p2 = lane & 7, u0 = lane >> 3;
  dft8<S, ZTOP>(v);
  { float2 t1 = twsgn(twt[lane], S), acc = t1;
    v[1] = cmul(v[1], acc);
    #pragma unroll
    for (int u = 2; u < 8; u++) { acc = cmul(acc, t1); v[u] = cmul(v[u], acc); } }
  __builtin_amdgcn_wave_barrier();
  #pragma unroll
  for (int u = 0; u < 8; u++) xch[u*68 + p2*8 + u0] = v[u];
  __builtin_amdgcn_wave_barrier();
  { const float4* rp = (const float4*)(xch + u0*68 + p2*8);
    #pragma unroll
    for (int q = 0; q < 4; q++) {
      float4 t = rp[q];
      v[2*q]   = make_float2(t.x, t.y);
      v[2*q+1] = make_float2(t.z, t.w);
    } }
  dft8<S, false>(v);
  { float2 t1 = twsgn(twt[p2 << 3], S), acc = t1;
    v[1] = cmul(v[1], acc);
    #pragma unroll
    for (int u = 2; u < 8; u++) { acc = cmul(acc, t1); v[u] = cmul(v[u], acc); } }
  __builtin_amdgcn_wave_barrier();
  #pragma unroll
  for (int u = 0; u < 8; u++) xch[u*68 + lane] = v[u];
  __builtin_amdgcn_wave_barrier();
  { const float4* rp = (const float4*)(xch + p2*68 + u0*8);
    #pragma unroll
    for (int q = 0; q < 4; q++) {
      float4 t = rp[q];
      v[2*q]   = make_float2(t.x, t.y);
      v[2*q+1] = make_float2(t.z, t.w);
    } }
  dft8<S, false>(v);
}

// --- B1: row FFT of mask (block 0 also does setup -> ws header) ------------
__global__ void __launch_bounds__(256, 6) k_b1(const float* mask, const float* prm,
                                               const float* sfx, const float* sfy,
                                               char* ws, float2* R1t) {
  int t = threadIdx.x, lane = t & 63, wv = t >> 6;
  __shared__ __align__(16) float2 lds[4*544];
  __shared__ __align__(16) float2 twt[512];
  build_twt(twt);
  if (blockIdx.x == 0) {                       // setup, overlapped w/ other blocks
    float*  sw  = (float*)lds;                 // scratch overlay (pre-FFT)
    float*  sxx = sw + 192; float* syy = sxx + 192; float* scw = syy + 192;
    double* so  = (double*)(sw + 768);
    int*    skp = (int*)(so + 176);
    if (t < 169) {
      float p = prm[t];
      float val = 1.f / (1.f + __expf(-8.f * p));
      float w = (val >= 0.001f) ? val : 0.f;
      double o = 0.0; float fx = 0.f, fy = 0.f;
      if (w > 0.f) {
        fx = sfx[t]; fy = sfy[t];
        double f2 = (double)fx*(double)fx + (double)fy*(double)fy;
        o = (double)w * sqrt((1.0 - 0.11390625 * f2) / (1.0 - 0.87890625 * f2));
      }
      sw[t] = w; so[t] = o; sxx[t] = fx; syy[t] = fy;
    }
    __syncthreads();
    if (t < 169) {                      // merge s with s'=(-fx,-fy): exact
      float w = sw[t];
      int keep = 0; float cw = w;
      if (w > 0.f) {
        float fx = sxx[t], fy = syy[t];
        int pr = -1;
        for (int s2 = 0; s2 < 169; s2++) {
          if (sw[s2] > 0.f && fabsf(sxx[s2] + fx) < 1e-5f
                           && fabsf(syy[s2] + fy) < 1e-5f) { pr = s2; break; }
        }
        if (pr < 0 || pr == t) keep = 1;
        else if (pr > t) { keep = 1; cw = w + sw[pr]; }
      }
      skp[t] = keep; scw[t] = cw;
    }
    __syncthreads();
    if (t == 0) {
      float* wsf = (float*)ws;
      double Sden = 0.0; int c = 0;
      for (int s = 0; s < 169; s++) {
        Sden += so[s];                               // norm over ALL valid
        if (skp[s]) { wsf[64+c] = scw[s]; wsf[320+c] = sxx[s]; wsf[576+c] = syy[s]; c++; }
      }
      ((int*)ws)[0] = c;
      wsf[1] = (float)(1.0 / (262144.0 * 1.44 * Sden));  // 512^2 refold
    }
  }
  __syncthreads();                              // setup scratch dead
  int y = blockIdx.x * 4 + wv;
  float2 v[8];
  #pragma unroll
  for (int q = 0; q < 8; q++) v[q] = make_float2(mask[y*512 + 64*q + lane], 0.f);
  wfft512<-1, false>(v, lane, lds + wv*544, twt);
  #pragma unroll
  for (int u = 0; u < 8; u++) {
    int k = (lane>>3) + 8*(lane&7) + 64*u;
    int beta = (k >= 392) ? (k - 392) : ((k <= 120) ? (k + 120) : -1);
    if (beta >= 0) R1t[beta*512 + y] = v[u];
  }
}

// --- B2: col FFT, keep window rows -> W[alpha][beta] -----------------------
__global__ void __launch_bounds__(256, 6) k_b2(const float2* R1t, float2* Wg) {
  int lane = threadIdx.x & 63, wv = threadIdx.x >> 6;
  int j = blockIdx.x * 4 + wv;                 // beta, grid 61 -> 0..243
  __shared__ __align__(16) float2 lds[4*544];
  __shared__ __align__(16) float2 twt[512];
  build_twt(twt);
  __syncthreads();
  float2 v[8];
  #pragma unroll
  for (int q = 0; q < 8; q++)
    v[q] = (j < 241) ? R1t[j*512 + 64*q + lane] : make_float2(0.f, 0.f);
  wfft512<-1, false>(v, lane, lds + wv*544, twt);
  if (j < 241) {
    #pragma unroll
    for (int u = 0; u < 8; u++) {
      int k = (lane>>3) + 8*(lane&7) + 64*u;
      int alpha = (k >= 392) ? (k - 392) : ((k <= 120) ? (k + 120) : -1);
      if (alpha >= 0) Wg[alpha*241 + j] = v[u];
    }
  }
}

// --- C1: task-loop; per source row IDFT of (W.*P)*sqrt(w)/512 -> T2 fp16 ---
__global__ void __launch_bounds__(256, 7) k_c1(const float2* Wg, const char* wsb,
                                               int base, int CH, __half2* T2) {
  const float* wsf = (const float*)wsb;
  __shared__ __align__(16) float2 lds[4*544];  // per-wave xch, reused as tout
  __shared__ __align__(16) float2 twt[512];
  __shared__ float FMt[241];
  build_twt(twt);
  if (threadIdx.x < 241)
    FMt[threadIdx.x] = (float)(((double)((int)threadIdx.x - 120)) / 100.0);
  __syncthreads();
  int active = *(const int*)wsb - base;
  if (active > CH) active = CH;
  int ntask = active * 31;
  int lane = threadIdx.x & 63, wv = threadIdx.x >> 6;
  float2* xch = lds + wv*544;
  for (int task = (int)blockIdx.x; task < ntask; task += (int)gridDim.x) {
    int sic  = task / 31;
    int tile = task % 31;                      // 8 alphas/tile, 2 phases of 4
    int slot = base + sic;
    float fx = wsf[320 + slot], fy = wsf[576 + slot];
    float sqw = __fsqrt_rn(wsf[64 + slot]) * 0.001953125f;  // sqrt(w)/512
    #pragma unroll
    for (int ph = 0; ph < 2; ph++) {
      int alpha = tile*8 + ph*4 + wv;
      bool arow = (alpha < 241);
      float Gf = __fadd_rn(arow ? FMt[alpha] : 0.f, fy);
      float g2 = __fmul_rn(Gf, Gf);
      bool active_row = arow && (g2 <= 1.0f);  // fl(G^2)>1 -> row all-zero
      float2 v[8];
      #pragma unroll
      for (int q = 0; q < 8; q++) v[q] = make_float2(0.f, 0.f);
      if (active_row) {
        #pragma unroll
        for (int q = 0; q < 4; q++) {          // n<241 -> q<4 only
          int n = 64*q + lane;
          if (n < 241) {
            float Ff = __fadd_rn(FMt[n], fx);
            float r2 = __fadd_rn(__fmul_rn(Ff, Ff), g2);  // np f32 semantics
            if (r2 <= 1.0f) {
              float num = fmaf(-0.11390625f, r2, 1.0f);
              float den = fmaf(-0.87890625f, r2, 1.0f);
              float P = __fsqrt_rn(__fsqrt_rn(__fdividef(num, den))) * sqw;
              float2 Wv = Wg[alpha*241 + n];
              v[q] = make_float2(P * Wv.x, P * Wv.y);
            }
          }
        }
        wfft512<1, true>(v, lane, xch, twt);
      }
      #pragma unroll
      for (int u = 0; u < 8; u++) {
        int xx = (lane>>3) + 8*(lane&7) + 64*u;
        xch[xx] = v[u];                        // zeros when inactive
      }
      __syncthreads();
      int colb = tile*8 + ph*4;
      if (colb < 244) {                        // tile30/ph1 would spill: skip
        #pragma unroll
        for (int r = 0; r < 2; r++) {
          int x = (int)threadIdx.x + 256*r;
          union { __half2 h[4]; float4 f; } u;
          #pragma unroll
          for (int wvi = 0; wvi < 4; wvi++) {
            float2 a = lds[wvi*544 + x];
            u.h[wvi] = __floats2half2_rn(a.x, a.y);
          }
          *(float4*)(T2 + ((size_t)sic*512 + x)*244 + colb) = u.f;
        }
      }
      __syncthreads();
    }
  }
}

// --- C2: per source col IDFT, acc += |AA'|^2 -------------------------------
__global__ void __launch_bounds__(256, 7) k_c2(const __half2* T2, const char* wsb,
                                               int base, int CH, int first,
                                               float* accbuf) {
  const int* cnt = (const int*)wsb;
  int part = blockIdx.x & (SPLIT-1);
  int xg   = blockIdx.x >> 3;                  // 0..127
  int lane = threadIdx.x & 63, wv = threadIdx.x >> 6;
  int x = xg*4 + wv;
  __shared__ __align__(16) float2 lds[4*544];
  __shared__ __align__(16) float2 twt[512];
  build_twt(twt);
  __syncthreads();
  float2* xch = lds + wv*544;
  int count = *cnt;
  float av[8] = {0.f,0.f,0.f,0.f,0.f,0.f,0.f,0.f};
  int sic = part;
  bool act = (sic < CH) && (base + sic < count);
  __half2 pv[4] = {{0.f,0.f},{0.f,0.f},{0.f,0.f},{0.f,0.f}};
  if (act) {
    const __half2* row = T2 + ((size_t)sic*512 + x)*244;
    #pragma unroll
    for (int q = 0; q < 4; q++) {
      int n = 64*q + lane;
      pv[q] = (n < 241) ? row[n] : __half2{0.f, 0.f};
    }
  }
  while (act) {
    float2 v[8];
    #pragma unroll
    for (int q = 0; q < 4; q++) { float2 f = __half22float2(pv[q]); v[q] = f; }
    #pragma unroll
    for (int q = 4; q < 8; q++) v[q] = make_float2(0.f, 0.f);
    int nsic = sic + SPLIT;
    act = (nsic < CH) && (base + nsic < count);
    if (act) {                                  // prefetch across the FFT
      const __half2* row = T2 + ((size_t)nsic*512 + x)*244;
      #pragma unroll
      for (int q = 0; q < 4; q++) {
        int n = 64*q + lane;
        pv[q] = (n < 241) ? row[n] : __half2{0.f, 0.f};
      }
    }
    wfft512<1, true>(v, lane, xch, twt);
    #pragma unroll
    for (int u = 0; u < 8; u++)
      av[u] += fmaf(v[u].x, v[u].x, v[u].y*v[u].y);
    sic = nsic;
  }
  float* a = accbuf + ((size_t)part << 18) + (size_t)x * 512;
  int y0 = (lane>>3) + 8*(lane&7);
  if (first) {
    #pragma unroll
    for (int u = 0; u < 8; u++) a[y0 + 64*u] = av[u];
  } else {
    #pragma unroll
    for (int u = 0; u < 8; u++) a[y0 + 64*u] += av[u];
  }
}

// --- D: transpose-tile, scale, doses, resist sigmoid -----------------------
__global__ void __launch_bounds__(256) k_final(const float* acc, const char* wsb,
                                               float* out) {
  __shared__ float tile[64][65];
  const float* wsf = (const float*)wsb;
  float scale = wsf[1];
  int x0 = (blockIdx.x & 7) * 64, y0 = (blockIdx.x >> 3) * 64;
  int j = threadIdx.x & 63, i0 = threadIdx.x >> 6;
  #pragma unroll
  for (int k = 0; k < 16; k++) {
    int i = i0 + 4*k;
    const float* ap = acc + (size_t)(x0 + i)*512 + y0 + j;
    float s = 0.f;
    #pragma unroll
    for (int p = 0; p < SPLIT; p++) s += ap[(size_t)p << 18];
    tile[i][j] = s;
  }
  __syncthreads();
  const float dd[3] = {0.9604f, 1.0f, 1.0404f};
  #pragma unroll
  for (int k = 0; k < 16; k++) {
    int yy = i0 + 4*k;
    float I = scale * tile[j][yy];
    int o = (y0 + yy)*512 + x0 + j;
    #pragma unroll
    for (int d = 0; d < 3; d++) {
      float Ik = dd[d] * I;
      out[(size_t)d*262144 + o] = Ik;
      out[(size_t)(3+d)*262144 + o] = 1.f / (1.f + __expf(-30.f*(Ik - 0.225f)));
    }
  }
}

extern "C" void kernel_launch(void* const* d_in, const int* in_sizes, int n_in,
                              void* d_out, int out_size, void* d_ws, size_t ws_size,
                              hipStream_t stream) {
  (void)in_sizes; (void)n_in; (void)out_size;
  const float* mask = (const float*)d_in[0];
  const float* prm  = (const float*)d_in[1];
  const float* sfx  = (const float*)d_in[2];
  const float* sfy  = (const float*)d_in[3];
  float* out = (float*)d_out;
  char*  ws  = (char*)d_ws;

  float*   acc = (float*)(ws + O_ACC);
  float2*  Wg  = (float2*)(ws + O_WIN);
  float2*  R1t = (float2*)(ws + O_R1);
  __half2* T2  = (__half2*)(ws + O_T2);

  k_b1<<<dim3(128), dim3(256), 0, stream>>>(mask, prm, sfx, sfy, ws, R1t);
  k_b2<<<dim3(61),  dim3(256), 0, stream>>>(R1t, Wg);

  size_t avail = (ws_size > O_T2) ? (ws_size - O_T2) : 0;
  int CH = (int)(avail / SLOT_BYTES);
  if (CH > 169) CH = 169;
  if (CH < 1)   CH = 1;
  for (int base = 0; base < 169; base += CH) {
    k_c1<<<dim3(1024),      dim3(256), 0, stream>>>(Wg, (const char*)ws, base, CH, T2);
    k_c2<<<dim3(128*SPLIT), dim3(256), 0, stream>>>(T2, (const char*)ws, base, CH,
                                                    (base == 0) ? 1 : 0, acc);
  }
  k_final<<<dim3(64), dim3(256), 0, stream>>>(acc, (const char*)ws, out);
}